// Round 15
// baseline (712.481 us; speedup 1.0000x reference)
//
#include <hip/hip_runtime.h>

// ---------- types ----------
typedef __bf16 bf16_t;
typedef bf16_t bf16x8 __attribute__((ext_vector_type(8)));
typedef float f32x4 __attribute__((ext_vector_type(4)));

__device__ inline f32x4 mfma16(bf16x8 a, bf16x8 b, f32x4 c) {
    return __builtin_amdgcn_mfma_f32_16x16x32_bf16(a, b, c, 0, 0, 0);
}

__device__ inline ushort f2bf(float f) {
    unsigned u = __builtin_bit_cast(unsigned, f);
    unsigned r = (u + 0x7FFFu + ((u >> 16) & 1u)) >> 16;
    return (ushort)r;
}

__device__ inline void gload_lds16(const void* g, void* l) {
    __builtin_amdgcn_global_load_lds(
        (const __attribute__((address_space(1))) void*)g,
        (__attribute__((address_space(3))) void*)l, 16, 0, 0);
}

// ---------- problem constants ----------
// B=16, Ktok=1024, D=512, HS=2048, HR=1024, E=8
// M=16384; units 0,1 = shared halves (scale 1), 2..9 = experts (scale rw[b,e])
#define M_TOT 16384
#define N_UNITS 10
#define UNIT_W (1024*512)
#define UNIT_W2 (2048*512)

// ---------- conversion kernels ----------
__global__ void k_cvt_x(const float* __restrict__ x, ushort* __restrict__ xb) {
    int i = (blockIdx.x * 256 + threadIdx.x) * 4;
    float4 v = *reinterpret_cast<const float4*>(x + i);
    ushort4 o;
    o.x = f2bf(v.x); o.y = f2bf(v.y); o.z = f2bf(v.z); o.w = f2bf(v.w);
    *reinterpret_cast<ushort4*>(xb + i) = o;
}

// gate/up -> merged-interleaved W2 [10][2048][512] bf16 (N-major).
// comb row n for real col c: n = (c>>4)*32 + IS_UP*16 + (c&15).
template<int IS_UP>
__global__ void k_trans2(const float* __restrict__ Wsh, const float* __restrict__ Wrt,
                         ushort* __restrict__ W2) {
    int u = blockIdx.z;
    const float* src; int stride;
    if (u < 2) { src = Wsh + u * 1024; stride = 2048; }
    else       { src = Wrt + (size_t)(u - 2) * 512 * 1024; stride = 1024; }
    __shared__ float t[64][65];
    int r0 = blockIdx.y * 64, c0 = blockIdx.x * 64;   // r0: k rows, c0: real cols
    int tid = threadIdx.x;
#pragma unroll
    for (int i = 0; i < 16; ++i) {
        int idx = i * 256 + tid;
        int r = idx >> 6, c = idx & 63;
        t[r][c] = src[(r0 + r) * stride + c0 + c];
    }
    __syncthreads();
    ushort* d = W2 + (size_t)u * UNIT_W2;
#pragma unroll
    for (int i = 0; i < 16; ++i) {
        int idx = i * 256 + tid;
        int r = idx >> 6, c = idx & 63;    // (c0+r)=real col, (r0+c)=k
        int rc = c0 + r;
        int n = ((rc >> 4) << 5) + IS_UP * 16 + (rc & 15);
        d[(size_t)n * 512 + (r0 + c)] = f2bf(t[c][r]);
    }
}

// down weights: transpose [ROWS x COLS] f32 -> [COLS x ROWS] bf16 (N-major)
template<int ROWS, int COLS>
__global__ void k_transD(const float* __restrict__ Wsh, const float* __restrict__ Wrt,
                         ushort* __restrict__ dst) {
    int u = blockIdx.z;
    const float* src = (u < 2) ? (Wsh + (size_t)u * ROWS * COLS)
                               : (Wrt + (size_t)(u - 2) * ROWS * COLS);
    int stride = COLS;
    __shared__ float t[64][65];
    int r0 = blockIdx.y * 64, c0 = blockIdx.x * 64;
    int tid = threadIdx.x;
#pragma unroll
    for (int i = 0; i < 16; ++i) {
        int idx = i * 256 + tid;
        int r = idx >> 6, c = idx & 63;
        t[r][c] = src[(r0 + r) * stride + c0 + c];
    }
    __syncthreads();
    ushort* d = dst + (size_t)u * ROWS * COLS;
#pragma unroll
    for (int i = 0; i < 16; ++i) {
        int idx = i * 256 + tid;
        int r = idx >> 6, c = idx & 63;
        d[(size_t)(c0 + r) * ROWS + (r0 + c)] = f2bf(t[c][r]);
    }
}

// ---------- GEMM 1: merged gate+up + SwiGLU. BK=64, XOR-swizzled LDS ----------
// A [M][512] bf16; W2 [10][2048][512] bf16; Hall [nu][M][1024] bf16.
// Block 128M x 128comb (=64 H cols), 4 waves (2x2), wave 64x64comb, acc[4][4].
// grid = nu * 128 * 16; block/unit = 2048 (ul = swz>>11).  [946 TF measured]
__global__ __launch_bounds__(256, 2) void gemm_gu3(
    const ushort* __restrict__ A, const ushort* __restrict__ W2,
    const float* __restrict__ bsg, const float* __restrict__ bsu,
    const float* __restrict__ brg, const float* __restrict__ bru,
    const float* __restrict__ rw, ushort* __restrict__ Hall, int unit_base) {
    __shared__ ushort lsA[128 * 64];
    __shared__ ushort lsB[128 * 64];
    const int nwg = gridDim.x, cpx = nwg >> 3;
    const int lid = blockIdx.x;
    const int swz = (lid & 7) * cpx + (lid >> 3);   // bijective: nwg % 8 == 0
    const int ul = swz >> 11;
    const int rem = swz & 2047;
    const int bm = (rem >> 4) * 128;     // M rows
    const int bnc = (rem & 15) * 128;    // combined col base
    const int ug = unit_base + ul;
    const ushort* Bw = W2 + (size_t)ug * UNIT_W2;

    const int tid = threadIdx.x;
    const int l = tid & 63, w = tid >> 6;
    const int wm = w >> 1, wn = w & 1;

    f32x4 acc[4][4] = {};

    for (int kk = 0; kk < 512; kk += 64) {
#pragma unroll
        for (int j = 0; j < 4; ++j) {
            int q = w * 4 + j;            // 1KB block 0..15
            int c = q * 64 + l;           // 16B chunk 0..1023
            int row = c >> 3, pc = c & 7;
            int lc = pc ^ (row & 7);      // source k-chunk (inverse swizzle)
            int koff = kk + lc * 8;
            gload_lds16(A  + (size_t)(bm + row) * 512 + koff,  lsA + q * 512);
            gload_lds16(Bw + (size_t)(bnc + row) * 512 + koff, lsB + q * 512);
        }
        __syncthreads();
#pragma unroll
        for (int s = 0; s < 2; ++s) {
            bf16x8 af[4], bf[4];
            int lcr = s * 4 + (l >> 4);
#pragma unroll
            for (int i = 0; i < 4; ++i) {
                int ar = wm * 64 + i * 16 + (l & 15);
                int br = wn * 64 + i * 16 + (l & 15);
                af[i] = *reinterpret_cast<const bf16x8*>(&lsA[ar * 64 + ((lcr ^ (ar & 7)) * 8)]);
                bf[i] = *reinterpret_cast<const bf16x8*>(&lsB[br * 64 + ((lcr ^ (br & 7)) * 8)]);
            }
#pragma unroll
            for (int mi = 0; mi < 4; ++mi)
#pragma unroll
                for (int ni = 0; ni < 4; ++ni)
                    acc[mi][ni] = mfma16(af[mi], bf[ni], acc[mi][ni]);
        }
        __syncthreads();
    }

    const float* bg = (ug < 2) ? (bsg + ug * 1024) : (brg + (ug - 2) * 1024);
    const float* bu = (ug < 2) ? (bsu + ug * 1024) : (bru + (ug - 2) * 1024);
    const float scale = (ug < 2) ? 1.0f : rw[(bm >> 10) * 8 + (ug - 2)];
    ushort* H = Hall + (size_t)ul * M_TOT * 1024;
#pragma unroll
    for (int p = 0; p < 2; ++p) {
        int colH = ((bnc + wn * 64) >> 1) + p * 16 + (l & 15);
        float bgv = bg[colH], buv = bu[colH];
#pragma unroll
        for (int mi = 0; mi < 4; ++mi)
#pragma unroll
            for (int r = 0; r < 4; ++r) {
                int row = bm + wm * 64 + mi * 16 + (l >> 4) * 4 + r;
                float g = acc[mi][2 * p][r] + bgv;
                float uu = acc[mi][2 * p + 1][r] + buv;
                float h = g / (1.0f + __expf(-g)) * uu * scale;
                H[(size_t)row * 1024 + colH] = f2bf(h);
            }
    }
}

// ---------- GEMM 2: down, TN=128, DOUBLE-BUFFERED prefetch (T3-min) ----------
// Hall [nu][M][1024] bf16; WD [10][512][1024] bf16; out [M][512] f32.
// Block 128x128, 4 waves, acc[4][4]. grid = 512. Pipeline: STAGE(t+1) issued
// BEFORE compute(t); implicit vmcnt(0)+barrier per step -> HBM latency hidden.
__global__ __launch_bounds__(256, 2) void gemm_dn5(
    const ushort* __restrict__ Hall, const ushort* __restrict__ WD,
    const float* __restrict__ bsd, const float* __restrict__ brd,
    const float* __restrict__ rw, float* __restrict__ out,
    int nu, int unit_base, int accumulate) {
    __shared__ ushort ls0A[128 * 64];
    __shared__ ushort ls0B[128 * 64];
    __shared__ ushort ls1A[128 * 64];
    __shared__ ushort ls1B[128 * 64];
    const int nwg = gridDim.x, cpx = nwg >> 3;
    const int lid = blockIdx.x;
    const int swz = (lid & 7) * cpx + (lid >> 3);
    const int bm = (swz >> 2) * 128;   // 128 M-tiles
    const int bn = (swz & 3) * 128;    // 4 N-tiles

    const int tid = threadIdx.x;
    const int l = tid & 63, w = tid >> 6;
    const int wm = w >> 1, wn = w & 1;

    f32x4 acc[4][4] = {};

    // step t: unit = t>>4, kk = (t&15)*64
    auto STAGE = [&](int t, ushort* dA, ushort* dB) {
        const ushort* Au = Hall + (size_t)(t >> 4) * M_TOT * 1024;
        const ushort* Bu = WD + (size_t)(unit_base + (t >> 4)) * UNIT_W;
        int kk = (t & 15) << 6;
#pragma unroll
        for (int j = 0; j < 4; ++j) {
            int q = w * 4 + j;
            int c = q * 64 + l;
            int row = c >> 3, pc = c & 7;
            int lc = pc ^ (row & 7);
            int koff = kk + lc * 8;
            gload_lds16(Au + (size_t)(bm + row) * 1024 + koff, dA + q * 512);
            gload_lds16(Bu + (size_t)(bn + row) * 1024 + koff, dB + q * 512);
        }
    };
    auto COMPUTE = [&](const ushort* sA, const ushort* sB) {
#pragma unroll
        for (int s = 0; s < 2; ++s) {
            bf16x8 af[4], bfr[4];
            int lcr = s * 4 + (l >> 4);
#pragma unroll
            for (int i = 0; i < 4; ++i) {
                int ar = wm * 64 + i * 16 + (l & 15);
                int br = wn * 64 + i * 16 + (l & 15);
                af[i] = *reinterpret_cast<const bf16x8*>(&sA[ar * 64 + ((lcr ^ (ar & 7)) * 8)]);
                bfr[i] = *reinterpret_cast<const bf16x8*>(&sB[br * 64 + ((lcr ^ (br & 7)) * 8)]);
            }
#pragma unroll
            for (int mi = 0; mi < 4; ++mi)
#pragma unroll
                for (int ni = 0; ni < 4; ++ni)
                    acc[mi][ni] = mfma16(af[mi], bfr[ni], acc[mi][ni]);
        }
    };

    const int nt = nu * 16;            // always even
    STAGE(0, ls0A, ls0B);
    __syncthreads();                   // drains vmcnt(0)
    for (int t = 0; t < nt; t += 2) {
        STAGE(t + 1, ls1A, ls1B);      // t+1 < nt always (nt even)
        COMPUTE(ls0A, ls0B);
        __syncthreads();               // waits STAGE(t+1) AFTER compute
        if (t + 2 < nt) STAGE(t + 2, ls0A, ls0B);
        COMPUTE(ls1A, ls1B);
        __syncthreads();
    }

    const int b = bm >> 10;
#pragma unroll
    for (int ni = 0; ni < 4; ++ni) {
        int col = bn + wn * 64 + ni * 16 + (l & 15);
        float bias = 0.0f;
        if (!accumulate) {
            bias = bsd[col];
#pragma unroll
            for (int e = 0; e < 8; ++e)
                bias += rw[b * 8 + e] * brd[e * 512 + col];
        }
#pragma unroll
        for (int mi = 0; mi < 4; ++mi)
#pragma unroll
            for (int r = 0; r < 4; ++r) {
                int grow = bm + wm * 64 + mi * 16 + (l >> 4) * 4 + r;
                if (accumulate) out[(size_t)grow * 512 + col] += acc[mi][ni][r];
                else            out[(size_t)grow * 512 + col]  = acc[mi][ni][r] + bias;
            }
    }
}

// ---------- launch ----------
extern "C" void kernel_launch(void* const* d_in, const int* in_sizes, int n_in,
                              void* d_out, int out_size, void* d_ws, size_t ws_size,
                              hipStream_t stream) {
    const float* x   = (const float*)d_in[0];
    const float* rw  = (const float*)d_in[1];
    const float* Wsg = (const float*)d_in[2];
    const float* bsg = (const float*)d_in[3];
    const float* Wsu = (const float*)d_in[4];
    const float* bsu = (const float*)d_in[5];
    const float* Wsd = (const float*)d_in[6];
    const float* bsd = (const float*)d_in[7];
    const float* Wrg = (const float*)d_in[8];
    const float* brg = (const float*)d_in[9];
    const float* Wru = (const float*)d_in[10];
    const float* bru = (const float*)d_in[11];
    const float* Wrd = (const float*)d_in[12];
    const float* brd = (const float*)d_in[13];
    float* out = (float*)d_out;

    const size_t xb_b  = (size_t)M_TOT * 512 * 2;              // 16.8 MB
    const size_t w2_b  = (size_t)N_UNITS * UNIT_W2 * 2;        // 21.0 MB
    const size_t wd_b  = (size_t)N_UNITS * UNIT_W * 2;         // 10.5 MB

    char* ws = (char*)d_ws;
    ushort* xb  = (ushort*)ws; ws += xb_b;
    ushort* W2  = (ushort*)ws; ws += w2_b;
    ushort* wdT = (ushort*)ws; ws += wd_b;
    ushort* Hb  = (ushort*)ws;

    const size_t base_b = xb_b + w2_b + wd_b;
    const size_t hall5 = (size_t)5 * M_TOT * 1024 * 2;   // 167.8 MB

    k_cvt_x<<<8192, 256, 0, stream>>>(x, xb);
    k_trans2<0><<<dim3(16, 8, 10), 256, 0, stream>>>(Wsg, Wrg, W2);
    k_trans2<1><<<dim3(16, 8, 10), 256, 0, stream>>>(Wsu, Wru, W2);
    k_transD<1024, 512><<<dim3(8, 16, 10), 256, 0, stream>>>(Wsd, Wrd, wdT);

    if (ws_size >= base_b + hall5) {
        // two unit-groups of 5, full-M Hall; second down accumulates (one RMW)
        for (int g = 0; g < 2; ++g) {
            gemm_gu3<<<10240, 256, 0, stream>>>(xb, W2, bsg, bsu, brg, bru, rw, Hb, g * 5);
            gemm_dn5<<<512, 256, 0, stream>>>(Hb, wdT, bsd, brd, rw, out, 5, g * 5, g);
        }
    } else {
        // per-unit fallback
        for (int u = 0; u < N_UNITS; ++u) {
            gemm_gu3<<<2048, 256, 0, stream>>>(xb, W2, bsg, bsu, brg, bru, rw, Hb, u);
            gemm_dn5<<<512, 256, 0, stream>>>(Hb, wdT, bsd, brd, rw, out, 1, u, u > 0 ? 1 : 0);
        }
    }
}